// Round 5
// baseline (420.060 us; speedup 1.0000x reference)
//
#include <hip/hip_runtime.h>
#include <stdint.h>
#include <stddef.h>

typedef __attribute__((ext_vector_type(4))) int i32x4;
typedef __attribute__((ext_vector_type(16))) int i32x16;

// ---------------- async global -> LDS (16B per lane) ----------------
__device__ __forceinline__ void gload_lds16(const void* g, void* l) {
    __builtin_amdgcn_global_load_lds(
        (const __attribute__((address_space(1))) void*)g,
        (__attribute__((address_space(3))) void*)l,
        16, 0, 0);
}

// ---------------- wave-wide butterfly reductions (all lanes get result) ----------------
__device__ __forceinline__ float waveAllMaxF(float v) {
#pragma unroll
    for (int m = 32; m > 0; m >>= 1) v = fmaxf(v, __shfl_xor(v, m, 64));
    return v;
}
__device__ __forceinline__ float waveAllMinF(float v) {
#pragma unroll
    for (int m = 32; m > 0; m >>= 1) v = fminf(v, __shfl_xor(v, m, 64));
    return v;
}
__device__ __forceinline__ int waveAllSumI(int v) {
#pragma unroll
    for (int m = 32; m > 0; m >>= 1) v += __shfl_xor(v, m, 64);
    return v;
}

// ---------------- weight quantization: row-wise symmetric int8 ----------------
// ONE WAVE per row, row register-resident, single pass, no LDS/barriers.
__global__ void __launch_bounds__(256) wquant_kernel(
    const float* __restrict__ W, int8_t* __restrict__ Wq,
    float* __restrict__ rscale, int* __restrict__ rsum, int K) {
    const int n = blockIdx.x * 4 + (threadIdx.x >> 6);
    const int lane = threadIdx.x & 63;
    const float4* row = (const float4*)(W + (size_t)n * K);
    int* out = (int*)(Wq + (size_t)n * K);

    if (K == 4096) {
        float4 v[16];
#pragma unroll
        for (int j = 0; j < 16; ++j) v[j] = row[lane + (j << 6)];

        float amax = 0.f;
#pragma unroll
        for (int j = 0; j < 16; ++j) {
            amax = fmaxf(amax, fmaxf(fmaxf(fabsf(v[j].x), fabsf(v[j].y)),
                                     fmaxf(fabsf(v[j].z), fabsf(v[j].w))));
        }
        amax = waveAllMaxF(amax);
        const float scale = (amax > 0.f) ? (amax / 127.0f) : 1.0f;

        int lsum = 0;
#pragma unroll
        for (int j = 0; j < 16; ++j) {
            int q0 = (int)fminf(fmaxf(rintf(v[j].x / scale), -127.f), 127.f);
            int q1 = (int)fminf(fmaxf(rintf(v[j].y / scale), -127.f), 127.f);
            int q2 = (int)fminf(fmaxf(rintf(v[j].z / scale), -127.f), 127.f);
            int q3 = (int)fminf(fmaxf(rintf(v[j].w / scale), -127.f), 127.f);
            lsum += q0 + q1 + q2 + q3;
            out[lane + (j << 6)] =
                (q0 & 255) | ((q1 & 255) << 8) | ((q2 & 255) << 16) | ((q3 & 255) << 24);
        }
        lsum = waveAllSumI(lsum);
        if (lane == 0) { rsum[n] = lsum; rscale[n] = scale; }
    } else {
        const int K4 = K >> 2;
        float amax = 0.f;
        for (int i = lane; i < K4; i += 64) {
            float4 f = row[i];
            amax = fmaxf(amax, fmaxf(fmaxf(fabsf(f.x), fabsf(f.y)),
                                     fmaxf(fabsf(f.z), fabsf(f.w))));
        }
        amax = waveAllMaxF(amax);
        const float scale = (amax > 0.f) ? (amax / 127.0f) : 1.0f;
        int lsum = 0;
        for (int i = lane; i < K4; i += 64) {
            float4 f = row[i];
            int q0 = (int)fminf(fmaxf(rintf(f.x / scale), -127.f), 127.f);
            int q1 = (int)fminf(fmaxf(rintf(f.y / scale), -127.f), 127.f);
            int q2 = (int)fminf(fmaxf(rintf(f.z / scale), -127.f), 127.f);
            int q3 = (int)fminf(fmaxf(rintf(f.w / scale), -127.f), 127.f);
            lsum += q0 + q1 + q2 + q3;
            out[i] = (q0 & 255) | ((q1 & 255) << 8) | ((q2 & 255) << 16) | ((q3 & 255) << 24);
        }
        lsum = waveAllSumI(lsum);
        if (lane == 0) { rsum[n] = lsum; rscale[n] = scale; }
    }
}

// ---------------- activation quantization: per-token asymmetric uint8 ----------------
__global__ void __launch_bounds__(256) aquant_kernel(
    const float* __restrict__ X, int8_t* __restrict__ Xq,
    float* __restrict__ cscale, int* __restrict__ azp, int K) {
    const int m = blockIdx.x * 4 + (threadIdx.x >> 6);
    const int lane = threadIdx.x & 63;
    const float4* row = (const float4*)(X + (size_t)m * K);
    int* out = (int*)(Xq + (size_t)m * K);

    if (K == 4096) {
        float4 v[16];
#pragma unroll
        for (int j = 0; j < 16; ++j) v[j] = row[lane + (j << 6)];

        float vmin = 3.402823466e38f, vmax = -3.402823466e38f;
#pragma unroll
        for (int j = 0; j < 16; ++j) {
            vmin = fminf(vmin, fminf(fminf(v[j].x, v[j].y), fminf(v[j].z, v[j].w)));
            vmax = fmaxf(vmax, fmaxf(fmaxf(v[j].x, v[j].y), fmaxf(v[j].z, v[j].w)));
        }
        vmin = waveAllMinF(vmin);
        vmax = waveAllMaxF(vmax);

        const float rng = vmax - vmin;
        const float scale = (rng > 0.f) ? (rng / 255.0f) : 1.0f;
        const float zp = rintf(-vmin / scale);

#pragma unroll
        for (int j = 0; j < 16; ++j) {
            int q0 = (int)fminf(fmaxf(rintf(v[j].x / scale) + zp, 0.f), 255.f) - 128;
            int q1 = (int)fminf(fmaxf(rintf(v[j].y / scale) + zp, 0.f), 255.f) - 128;
            int q2 = (int)fminf(fmaxf(rintf(v[j].z / scale) + zp, 0.f), 255.f) - 128;
            int q3 = (int)fminf(fmaxf(rintf(v[j].w / scale) + zp, 0.f), 255.f) - 128;
            out[lane + (j << 6)] =
                (q0 & 255) | ((q1 & 255) << 8) | ((q2 & 255) << 16) | ((q3 & 255) << 24);
        }
        if (lane == 0) { cscale[m] = scale; azp[m] = 128 - (int)zp; }
    } else {
        const int K4 = K >> 2;
        float vmin = 3.402823466e38f, vmax = -3.402823466e38f;
        for (int i = lane; i < K4; i += 64) {
            float4 f = row[i];
            vmin = fminf(vmin, fminf(fminf(f.x, f.y), fminf(f.z, f.w)));
            vmax = fmaxf(vmax, fmaxf(fmaxf(f.x, f.y), fmaxf(f.z, f.w)));
        }
        vmin = waveAllMinF(vmin);
        vmax = waveAllMaxF(vmax);
        const float rng = vmax - vmin;
        const float scale = (rng > 0.f) ? (rng / 255.0f) : 1.0f;
        const float zp = rintf(-vmin / scale);
        for (int i = lane; i < K4; i += 64) {
            float4 f = row[i];
            int q0 = (int)fminf(fmaxf(rintf(f.x / scale) + zp, 0.f), 255.f) - 128;
            int q1 = (int)fminf(fmaxf(rintf(f.y / scale) + zp, 0.f), 255.f) - 128;
            int q2 = (int)fminf(fmaxf(rintf(f.z / scale) + zp, 0.f), 255.f) - 128;
            int q3 = (int)fminf(fmaxf(rintf(f.w / scale) + zp, 0.f), 255.f) - 128;
            out[i] = (q0 & 255) | ((q1 & 255) << 8) | ((q2 & 255) << 16) | ((q3 & 255) << 24);
        }
        if (lane == 0) { cscale[m] = scale; azp[m] = 128 - (int)zp; }
    }
}

// ---------------- int8 GEMM: 256x256 tile, 8 waves, round-2 schedule, 32x32x32 MFMA ----------------
// A: [M,K] i8 (Xq), B: [N,K] i8 (Wq).
// Y[m,n] = (dot_i8(A[m],B[n]) + azp[m]*rsum[n]) * cs[m]*rs[n] + bias[n]
//
// Schedule REVERTED to the verified round-2 form (145 us): stage tile t+1 first,
// compute tile t, single __syncthreads per tile (8-phase variant measured -6%).
// MFMA shape switched 16x16x64 -> 32x32x32 (4404 vs 3944 TOPS, half the
// instruction count at the same LDS read volume).
//
// 32x32x32 i8 operand layout (scaled analog of the verified 16x16x64 usage):
//   A-frag: lane holds A[row = lane&31][k0 + (lane>>5)*16 .. +15]  (16B, i32x4)
//   B-frag: symmetric on the [N,K] row-major Wq.
//   C/D (16 regs): col = lane&31, row = (reg&3) + 8*(reg>>2) + 4*(lane>>5)
//   [guide m74/m101, dtype-independent].
// XOR swizzle unchanged: fragment row = lane (mod 8) in both shapes -> axor = lane&7.
__global__ void __launch_bounds__(512, 2) gemm_i8_kernel(
    const int8_t* __restrict__ A, const int8_t* __restrict__ B,
    float* __restrict__ Y,
    const float* __restrict__ cs, const int* __restrict__ azp,
    const float* __restrict__ rs, const int* __restrict__ rsum,
    const float* __restrict__ bias, int M, int N, int K) {
    extern __shared__ int8_t smem[];  // [2][A:32KB | B:32KB]

    const int tid = threadIdx.x;
    const int lane = tid & 63;
    const int wave = tid >> 6;
    const int wm = wave >> 2;   // 0..1  (M side, 128 rows each)
    const int wn = wave & 3;    // 0..3  (N side, 64 cols each)
    const int l31 = lane & 31;  // fragment row/col
    const int half = lane >> 5; // k-half select
    const int axor = lane & 7;  // swizzle XOR (row = lane mod 8)

    // ---- XCD-aware bijective block swizzle ----
    const int nwg = gridDim.x * gridDim.y;
    int wid = blockIdx.y * gridDim.x + blockIdx.x;
    if ((nwg & 7) == 0) wid = (wid & 7) * (nwg >> 3) + (wid >> 3);
    const int bm = (wid % gridDim.x) * 256;
    const int bn = (wid / gridDim.x) * 256;

    const int8_t* Ag = A + (size_t)bm * K;
    const int8_t* Bg = B + (size_t)bn * K;

    // ---- staging map (round-2, verified 0 bank conflicts): lane-linear LDS dest,
    //      swizzle carried on the global source column ----
    const int sr = tid >> 3;
    const int sc = tid & 7;
    const int csrc = (sc ^ (sr & 7)) << 4;

    i32x16 acc[4][2] = {};
    const int NT = K >> 7;  // K-tiles of 128 bytes

    // prologue: stage tile 0 into buffer 0
    {
        int8_t* dA = smem;
        int8_t* dB = smem + 32768;
#pragma unroll
        for (int q = 0; q < 4; ++q) {
            const int r = q * 64 + sr;
            gload_lds16(Ag + (size_t)r * K + csrc, dA + r * 128 + (sc << 4));
            gload_lds16(Bg + (size_t)r * K + csrc, dB + r * 128 + (sc << 4));
        }
    }
    __syncthreads();  // vmcnt(0) drain + barrier

    const int aBase = (wm * 128 + l31) * 128;  // + i*32*128
    const int bBase = (wn * 64 + l31) * 128;   // + j*32*128

    int buf = 0;
    for (int t = 0; t < NT; ++t) {
        // 1) issue next tile's staging first (overlaps with this tile's compute)
        if (t + 1 < NT) {
            const int k0 = (t + 1) << 7;
            int8_t* dA = smem + (buf ^ 1) * 65536;
            int8_t* dB = dA + 32768;
#pragma unroll
            for (int q = 0; q < 4; ++q) {
                const int r = q * 64 + sr;
                gload_lds16(Ag + (size_t)r * K + (k0 + csrc), dA + r * 128 + (sc << 4));
                gload_lds16(Bg + (size_t)r * K + (k0 + csrc), dB + r * 128 + (sc << 4));
            }
        }

        // 2) compute current tile: 4 k-steps of 32, 8 MFMA each
        const int8_t* Ab = smem + buf * 65536;
        const int8_t* Bb = Ab + 32768;
#pragma unroll
        for (int ks = 0; ks < 4; ++ks) {
            const int off = (((ks << 1) | half) ^ axor) << 4;  // swizzled 16B slot
            i32x4 af[4], bf[2];
#pragma unroll
            for (int i = 0; i < 4; ++i)
                af[i] = *(const i32x4*)&Ab[aBase + i * 4096 + off];
#pragma unroll
            for (int j = 0; j < 2; ++j)
                bf[j] = *(const i32x4*)&Bb[bBase + j * 4096 + off];
#pragma unroll
            for (int i = 0; i < 4; ++i)
#pragma unroll
                for (int j = 0; j < 2; ++j)
                    acc[i][j] = __builtin_amdgcn_mfma_i32_32x32x32_i8(af[i], bf[j], acc[i][j], 0, 0, 0);
        }

        // 3) one barrier per tile: drains vmcnt (next tile staged) + lgkmcnt (reads done)
        __syncthreads();
        buf ^= 1;
    }

    // epilogue: 32x32 C/D layout: col = lane&31, row = (r&3) + 8*(r>>2) + 4*half
#pragma unroll
    for (int i = 0; i < 4; ++i) {
        const int mb = bm + wm * 128 + i * 32 + 4 * half;
#pragma unroll
        for (int j = 0; j < 2; ++j) {
            const int n = bn + wn * 64 + j * 32 + l31;
            const float rsn = rs[n];
            const int rsn_i = rsum[n];
            const float bn_f = bias[n];
#pragma unroll
            for (int r = 0; r < 16; ++r) {
                const int m = mb + (r & 3) + 8 * (r >> 2);
                const int tot = acc[i][j][r] + azp[m] * rsn_i;
                Y[(size_t)m * N + n] = fmaf((float)tot, cs[m] * rsn, bn_f);
            }
        }
    }
}

// ---------------- launch ----------------
extern "C" void kernel_launch(void* const* d_in, const int* in_sizes, int n_in,
                              void* d_out, int out_size, void* d_ws, size_t ws_size,
                              hipStream_t stream) {
    const float* x = (const float*)d_in[0];
    const float* w = (const float*)d_in[1];
    const float* bias = (const float*)d_in[2];
    float* y = (float*)d_out;

    const int N = in_sizes[2];            // 4096
    const int K = in_sizes[1] / N;        // 4096
    const int M = in_sizes[0] / K;        // 8192

    uint8_t* ws = (uint8_t*)d_ws;
    int8_t* Wq = (int8_t*)ws;                                  // N*K   int8
    int8_t* Xq = (int8_t*)(ws + (size_t)N * K);                // M*K   int8
    uint8_t* p = ws + (size_t)N * K + (size_t)M * K;
    p = (uint8_t*)(((uintptr_t)p + 255) & ~(uintptr_t)255);
    float* rscale = (float*)p;  p += (size_t)N * sizeof(float);
    int*   rsum   = (int*)p;    p += (size_t)N * sizeof(int);
    float* cscale = (float*)p;  p += (size_t)M * sizeof(float);
    int*   azp    = (int*)p;    p += (size_t)M * sizeof(int);

    static int lds_cfg = 0;
    if (!lds_cfg) {
        (void)hipFuncSetAttribute((const void*)gemm_i8_kernel,
                                  hipFuncAttributeMaxDynamicSharedMemorySize, 131072);
        lds_cfg = 1;
    }

    wquant_kernel<<<N / 4, 256, 0, stream>>>(w, Wq, rscale, rsum, K);
    aquant_kernel<<<M / 4, 256, 0, stream>>>(x, Xq, cscale, azp, K);

    dim3 grid(M / 256, N / 256);
    gemm_i8_kernel<<<grid, 512, 131072, stream>>>(Xq, Wq, y, cscale, azp,
                                                  rscale, rsum, bias, M, N, K);
}